// Round 1
// baseline (481.173 us; speedup 1.0000x reference)
//
#include <hip/hip_runtime.h>
#include <math.h>

// ChebConv2D on MI355X (gfx950).
// Restructured algebra: height-analysis is done in width-coefficient space:
//   m[b,o,h,kw]   = sum_c (sum_w x[b,c,h,w] Tp_w[kw,w]) W_w[c,o,kw]     (K1)
//   d[b,o,kh,kw]  = sum_h Tp_h[kh,h] m[b,o,h,kw]                        (K2 phase 1)
//   e[b,f,kh,kw]  = sum_o W_h[o,f,kh] d[b,o,kh,kw]                      (K2 phase 2)
//   out[b,f,h,w]  = sum_kh Te_h[h,kh] sum_kw e[b,f,kh,kw] Te_w[w,kw]    (K3)
// => only intermediates are m (9.4 MB) and e (0.66 MB); HBM ~ x + out.

#define K9 9

// ---------------- setup: Chebyshev matrices (Tp = pinv(T), Te = T) ----------
__global__ __launch_bounds__(128) void setup_cheb(float* __restrict__ Tp,
                                                  float* __restrict__ Te) {
    __shared__ double Tsh[128 * K9];
    __shared__ double GA[9][18];   // augmented [G | I] -> [I | G^-1]
    int tid = threadIdx.x;
    {
        int n = tid;
        float xf = (float)((double)n / 127.0);       // np.linspace(0,1,128)
        float xn = 2.0f * xf - 1.0f;
        const float lo = (float)(-1.0 + 1e-6);
        const float hi = (float)(1.0 - 1e-6);
        xn = fminf(fmaxf(xn, lo), hi);
        float th = acosf(xn);
        for (int k = 0; k < K9; ++k) {
            float tv = cosf(th * (float)k);          // f32 like numpy, then f64 cast
            Te[n * K9 + k] = tv;
            Tsh[n * K9 + k] = (double)tv;
        }
    }
    __syncthreads();
    if (tid < 81) {                                   // G = T^T T  (9x9, f64)
        int i = tid / 9, j = tid % 9;
        double s = 0.0;
        for (int n = 0; n < 128; ++n) s += Tsh[n * K9 + i] * Tsh[n * K9 + j];
        GA[i][j] = s;
    }
    __syncthreads();
    if (tid == 0) {                                   // Gauss-Jordan, partial pivot
        for (int i = 0; i < 9; ++i)
            for (int j = 0; j < 9; ++j)
                GA[i][9 + j] = (i == j) ? 1.0 : 0.0;
        for (int col = 0; col < 9; ++col) {
            int piv = col;
            double best = fabs(GA[col][col]);
            for (int r = col + 1; r < 9; ++r) {
                double v = fabs(GA[r][col]);
                if (v > best) { best = v; piv = r; }
            }
            if (piv != col)
                for (int j = 0; j < 18; ++j) {
                    double t = GA[col][j]; GA[col][j] = GA[piv][j]; GA[piv][j] = t;
                }
            double inv = 1.0 / GA[col][col];
            for (int j = 0; j < 18; ++j) GA[col][j] *= inv;
            for (int r = 0; r < 9; ++r)
                if (r != col) {
                    double f = GA[r][col];
                    for (int j = 0; j < 18; ++j) GA[r][j] -= f * GA[col][j];
                }
        }
    }
    __syncthreads();
    // Tp[k][n] = sum_j Ginv[k][j] * T[n][j]  (pinv = (T^T T)^-1 T^T)
    for (int idx = tid; idx < K9 * 128; idx += 128) {
        int k = idx / 128, n = idx % 128;
        double s = 0.0;
        for (int j = 0; j < 9; ++j) s += GA[k][9 + j] * Tsh[n * K9 + j];
        Tp[idx] = (float)s;
    }
}

// ---------------- setup: weight transposes for coalesced reads --------------
// Wt_w[k][c][o] <- W_w[c][o][k];  Wh_t[k][o][f] <- W_h[o][f][k]
__global__ __launch_bounds__(256) void transpose_w(const float* __restrict__ Ww,
                                                   const float* __restrict__ Wh,
                                                   float* __restrict__ Wt_w,
                                                   float* __restrict__ Wh_t) {
    int gid = blockIdx.x * 256 + threadIdx.x;
    if (gid < 36864) {
        int k = gid / 4096, r = gid % 4096, c = r / 64, o = r % 64;
        Wt_w[gid] = Ww[(c * 64 + o) * 9 + k];
    } else if (gid < 73728) {
        int g = gid - 36864;
        int k = g / 4096, r = g % 4096, o = r / 64, f = r % 64;
        Wh_t[g] = Wh[(o * 64 + f) * 9 + k];
    }
}

// ---------------- K1: x -> m  (width analysis + channel mix) ----------------
// block = (b, group of 4 h rows). m layout: [b][h][kw][o].
__global__ __launch_bounds__(256) void k1_width(const float* __restrict__ x,
                                                const float* __restrict__ Wt_w,
                                                const float* __restrict__ Tp,
                                                float* __restrict__ m_ws) {
    __shared__ float xs[64 * 132];        // one h row, [c][w] pad 132 (b128-aligned)
    __shared__ float tpt[128 * K9];       // Tp transposed [w][k], stride 9
    __shared__ float cs[4 * 576];         // coeffs [hh][c][k]
    int tid = threadIdx.x;
    int b  = blockIdx.x >> 5;
    int h0 = (blockIdx.x & 31) << 2;
    for (int i = tid; i < 1152; i += 256) {
        int k = i >> 7, w = i & 127;
        tpt[w * 9 + k] = Tp[i];
    }
    const float* xb = x + (size_t)b * 1048576 + (size_t)h0 * 128;
    for (int hh = 0; hh < 4; ++hh) {
        // stage row hh: 2048 float4, coalesced; LDS writes b128 conflict-free
        for (int j = 0; j < 8; ++j) {
            int e = j * 256 + tid;             // float4 index
            int c = e >> 5;
            int w4 = (e & 31) << 2;
            float4 v = *(const float4*)(xb + (size_t)c * 16384 + hh * 128 + w4);
            *(float4*)&xs[c * 132 + w4] = v;
        }
        __syncthreads();
        // analysis: c[c][k] = sum_w xs[c][w] * Tp[k][w]
        for (int idx = tid; idx < 576; idx += 256) {
            int c = idx / 9, k = idx - c * 9;    // lanes: broadcast xs, stride-9 tpt
            const float* xr = &xs[c * 132];
            float acc = 0.f;
            for (int w = 0; w < 128; ++w) acc = fmaf(xr[w], tpt[w * 9 + k], acc);
            cs[hh * 576 + idx] = acc;            // idx == c*9+k
        }
        __syncthreads();
    }
    // channel mix: m[o][k] = sum_c cs[c][k] * Wt_w[k][c][o], 4 h rows share W reads
    float* mrow = m_ws + (size_t)(b * 128 + h0) * 576;
    for (int idx = tid; idx < 576; idx += 256) {
        int o = idx & 63, k = idx >> 6;
        const float* wt = Wt_w + k * 4096 + o;   // +c*64, lanes over o: coalesced
        float a0 = 0.f, a1 = 0.f, a2 = 0.f, a3 = 0.f;
        for (int c = 0; c < 64; ++c) {
            float wv = wt[c * 64];
            float i0 = cs[0 * 576 + c * 9 + k];  // broadcast (k uniform per wave)
            float i1 = cs[1 * 576 + c * 9 + k];
            float i2 = cs[2 * 576 + c * 9 + k];
            float i3 = cs[3 * 576 + c * 9 + k];
            a0 = fmaf(i0, wv, a0); a1 = fmaf(i1, wv, a1);
            a2 = fmaf(i2, wv, a2); a3 = fmaf(i3, wv, a3);
        }
        mrow[0 * 576 + idx] = a0;                // m layout per row: [kw][o]
        mrow[1 * 576 + idx] = a1;
        mrow[2 * 576 + idx] = a2;
        mrow[3 * 576 + idx] = a3;
    }
}

// ---------------- K2: m -> e  (height analysis + channel mix) ---------------
// block = b (32 blocks). d in registers, chunked LDS staging of m.
__global__ __launch_bounds__(256) void k2_height(const float* __restrict__ m_ws,
                                                 const float* __restrict__ Wh_t,
                                                 const float* __restrict__ Tp,
                                                 float* __restrict__ e_ws) {
    __shared__ float tpt[128 * K9];   // Tp transposed [h][kh]
    __shared__ float mch[16 * 576];   // chunk [hh][o][kw]
    __shared__ float dl[5184];        // d [o][kh][kw]
    int tid = threadIdx.x;
    int b = blockIdx.x;
    for (int i = tid; i < 1152; i += 256) {
        int k = i >> 7, h = i & 127;
        tpt[h * 9 + k] = Tp[i];
    }
    int p0 = tid, p1 = tid + 256, p2 = tid + 512;   // pair index = o*9+kw
    bool v2 = (p2 < 576);
    float d0[9], d1[9], d2[9];
#pragma unroll
    for (int k = 0; k < 9; ++k) { d0[k] = 0.f; d1[k] = 0.f; d2[k] = 0.f; }
    const float* mb = m_ws + (size_t)b * 73728;
    for (int hc = 0; hc < 8; ++hc) {
        __syncthreads();   // protects tpt (hc=0) and mch from prior readers
        for (int i = tid; i < 9216; i += 256) {
            int hh = i / 576, r = i - hh * 576;
            int kw = r >> 6, o = r & 63;
            mch[hh * 576 + o * 9 + kw] = mb[hc * 9216 + i];   // [hh][o][kw]
        }
        __syncthreads();
        for (int hh = 0; hh < 16; ++hh) {
            const float* tr = &tpt[(hc * 16 + hh) * 9];
            float t[9];
#pragma unroll
            for (int k = 0; k < 9; ++k) t[k] = tr[k];
            float mv0 = mch[hh * 576 + p0];     // consecutive addrs: conflict-free
            float mv1 = mch[hh * 576 + p1];
            float mv2 = v2 ? mch[hh * 576 + p2] : 0.f;
#pragma unroll
            for (int k = 0; k < 9; ++k) {
                d0[k] = fmaf(t[k], mv0, d0[k]);
                d1[k] = fmaf(t[k], mv1, d1[k]);
                d2[k] = fmaf(t[k], mv2, d2[k]);
            }
        }
    }
    {
        int o0 = p0 / 9, kw0 = p0 - o0 * 9;
        int o1 = p1 / 9, kw1 = p1 - o1 * 9;
        int o2 = p2 / 9, kw2 = p2 - o2 * 9;
#pragma unroll
        for (int k = 0; k < 9; ++k) {
            dl[o0 * 81 + k * 9 + kw0] = d0[k];
            dl[o1 * 81 + k * 9 + kw1] = d1[k];
            if (v2) dl[o2 * 81 + k * 9 + kw2] = d2[k];
        }
    }
    __syncthreads();
    // e[f][kh][kw] = sum_o Wh_t[kh][o][f] * d[o][kh][kw]
    float* eb = e_ws + (size_t)b * 5184;
    for (int idx = tid; idx < 5184; idx += 256) {
        int f = idx & 63, r = idx >> 6;        // r = kh*9+kw
        int kh = r / 9;
        const float* wh = Wh_t + kh * 4096 + f;   // lanes over f: coalesced
        float acc = 0.f;
        for (int o = 0; o < 64; ++o) acc = fmaf(wh[o * 64], dl[o * 81 + r], acc);
        eb[f * 81 + r] = acc;                  // e layout [b][f][kh*9+kw]
    }
}

// ---------------- K3: e -> out (separable synthesis) ------------------------
// block = (b, f). f1[kh][w] = sum_kw e*Te_w; out = sum_kh Te_h*f1.
__global__ __launch_bounds__(256) void k3_synth(const float* __restrict__ e_ws,
                                                const float* __restrict__ Te,
                                                float* __restrict__ out) {
    __shared__ float tes[1152];   // Te [n][k], stride 9
    __shared__ float el[81];
    __shared__ float f1[9 * 128];
    int tid = threadIdx.x;
    int bf = blockIdx.x;
    for (int i = tid; i < 1152; i += 256) tes[i] = Te[i];
    if (tid < 81) el[tid] = e_ws[(size_t)bf * 81 + tid];
    __syncthreads();
    for (int idx = tid; idx < 1152; idx += 256) {
        int kh = idx >> 7, w = idx & 127;
        float acc = 0.f;
#pragma unroll
        for (int kw = 0; kw < 9; ++kw)
            acc = fmaf(el[kh * 9 + kw], tes[w * 9 + kw], acc);
        f1[kh * 128 + w] = acc;
    }
    __syncthreads();
    int w4 = (tid & 31) << 2;
    int hg = tid >> 5;                 // 0..7
    float4 fr[9];
#pragma unroll
    for (int k = 0; k < 9; ++k) fr[k] = *(const float4*)&f1[k * 128 + w4];
    float* ob = out + (size_t)bf * 16384;
    for (int h = hg; h < 128; h += 8) {
        const float* th = &tes[h * 9];
        float4 acc = make_float4(0.f, 0.f, 0.f, 0.f);
#pragma unroll
        for (int k = 0; k < 9; ++k) {
            float t = th[k];           // broadcast read
            acc.x = fmaf(t, fr[k].x, acc.x);
            acc.y = fmaf(t, fr[k].y, acc.y);
            acc.z = fmaf(t, fr[k].z, acc.z);
            acc.w = fmaf(t, fr[k].w, acc.w);
        }
        *(float4*)(ob + h * 128 + w4) = acc;   // coalesced float4 store
    }
}

extern "C" void kernel_launch(void* const* d_in, const int* in_sizes, int n_in,
                              void* d_out, int out_size, void* d_ws, size_t ws_size,
                              hipStream_t stream) {
    (void)in_sizes; (void)n_in; (void)out_size; (void)ws_size;
    const float* x  = (const float*)d_in[0];
    const float* Ww = (const float*)d_in[1];
    const float* Wh = (const float*)d_in[2];
    float* out = (float*)d_out;
    float* ws = (float*)d_ws;
    // workspace layout (floats): total 2,601,216 (~10.4 MB)
    float* Tp   = ws;                       // 1152
    float* Te   = ws + 1152;                // 1152
    float* Wt_w = ws + 2304;                // 36864
    float* Wh_t = ws + 39168;               // 36864
    float* m_ws = ws + 76032;               // 2,359,296
    float* e_ws = ws + 76032 + 2359296;     // 165,888

    setup_cheb<<<1, 128, 0, stream>>>(Tp, Te);
    transpose_w<<<288, 256, 0, stream>>>(Ww, Wh, Wt_w, Wh_t);
    k1_width<<<1024, 256, 0, stream>>>(x, Wt_w, Tp, m_ws);
    k2_height<<<32, 256, 0, stream>>>(m_ws, Wh_t, Tp, e_ws);
    k3_synth<<<2048, 256, 0, stream>>>(e_ws, Te, out);
}

// Round 2
// 354.645 us; speedup vs baseline: 1.3568x; 1.3568x over previous
//
#include <hip/hip_runtime.h>
#include <math.h>

// ChebConv2D on MI355X (gfx950).
//   m[b,h,kw,o]   = sum_c (sum_w x[b,c,h,w] Tp_w[kw,w]) W_w[c,o,kw]     (K1)
//   d[b,kh,kw,o]  = sum_h Tp_h[kh,h] m[b,h,kw,o]                        (K2 ph1)
//   e[b,f,kh,kw]  = sum_o W_h[o,f,kh] d[b,kh,kw,o]                      (K2 ph2)
//   out[b,f,h,w]  = sum_kh Te_h[h,kh] sum_kw e[b,f,kh,kw] Te_w[w,kw]    (K3)

#define K9 9

// ---------------- setup: Chebyshev matrices (Tp = pinv(T), Te = T) ----------
__global__ __launch_bounds__(128) void setup_cheb(float* __restrict__ Tp,
                                                  float* __restrict__ Te,
                                                  float* __restrict__ Tpt16) {
    __shared__ double Tsh[128 * K9];
    __shared__ double GA[9][18];   // augmented [G | I] -> [I | G^-1]
    int tid = threadIdx.x;
    {
        int n = tid;
        float xf = (float)((double)n / 127.0);       // np.linspace(0,1,128)
        float xn = 2.0f * xf - 1.0f;
        const float lo = (float)(-1.0 + 1e-6);
        const float hi = (float)(1.0 - 1e-6);
        xn = fminf(fmaxf(xn, lo), hi);
        float th = acosf(xn);
        for (int k = 0; k < K9; ++k) {
            float tv = cosf(th * (float)k);          // f32 like numpy, then f64 cast
            Te[n * K9 + k] = tv;
            Tsh[n * K9 + k] = (double)tv;
        }
    }
    __syncthreads();
    if (tid < 81) {                                   // G = T^T T  (9x9, f64)
        int i = tid / 9, j = tid % 9;
        double s = 0.0;
        for (int n = 0; n < 128; ++n) s += Tsh[n * K9 + i] * Tsh[n * K9 + j];
        GA[i][j] = s;
    }
    __syncthreads();
    if (tid == 0) {                                   // Gauss-Jordan, partial pivot
        for (int i = 0; i < 9; ++i)
            for (int j = 0; j < 9; ++j)
                GA[i][9 + j] = (i == j) ? 1.0 : 0.0;
        for (int col = 0; col < 9; ++col) {
            int piv = col;
            double best = fabs(GA[col][col]);
            for (int r = col + 1; r < 9; ++r) {
                double v = fabs(GA[r][col]);
                if (v > best) { best = v; piv = r; }
            }
            if (piv != col)
                for (int j = 0; j < 18; ++j) {
                    double t = GA[col][j]; GA[col][j] = GA[piv][j]; GA[piv][j] = t;
                }
            double inv = 1.0 / GA[col][col];
            for (int j = 0; j < 18; ++j) GA[col][j] *= inv;
            for (int r = 0; r < 9; ++r)
                if (r != col) {
                    double f = GA[r][col];
                    for (int j = 0; j < 18; ++j) GA[r][j] -= f * GA[col][j];
                }
        }
    }
    __syncthreads();
    // Tp[k][n] = sum_j Ginv[k][j] * T[n][j]  (pinv = (T^T T)^-1 T^T)
    for (int idx = tid; idx < K9 * 128; idx += 128) {
        int k = idx / 128, n = idx % 128;
        double s = 0.0;
        for (int j = 0; j < 9; ++j) s += GA[k][9 + j] * Tsh[n * K9 + j];
        float sv = (float)s;
        Tp[idx] = sv;
        Tpt16[n * 16 + k] = sv;      // transposed, padded row of 16 for s_load
    }
}

// ---------------- setup: weight transposes for coalesced reads --------------
// Wt_w[k][c][o] <- W_w[c][o][k];  Wh_t[k][o][f] <- W_h[o][f][k]
__global__ __launch_bounds__(256) void transpose_w(const float* __restrict__ Ww,
                                                   const float* __restrict__ Wh,
                                                   float* __restrict__ Wt_w,
                                                   float* __restrict__ Wh_t) {
    int gid = blockIdx.x * 256 + threadIdx.x;
    if (gid < 36864) {
        int k = gid / 4096, r = gid % 4096, c = r / 64, o = r % 64;
        Wt_w[gid] = Ww[(c * 64 + o) * 9 + k];
    } else if (gid < 73728) {
        int g = gid - 36864;
        int k = g / 4096, r = g % 4096, o = r / 64, f = r % 64;
        Wh_t[g] = Wh[(o * 64 + f) * 9 + k];
    }
}

// ---------------- K1: x -> m  (width analysis + channel mix) ----------------
// block = (b, group of 4 h rows), 256 threads. m layout: [b][h][kw][o].
// Analysis: thread=(row-in-chunk hh2, w-half q, channel c). x staged at stride
// 129 (lane-over-c reads 2-way -> free). Tp read via uniform addresses
// (readfirstlane(q)) from Tpt16 -> scalar loads, 1 LDS read per 9 FMA.
__global__ __launch_bounds__(256, 2) void k1_width(const float* __restrict__ x,
                                                   const float* __restrict__ Wt_w,
                                                   const float* __restrict__ Tpt16,
                                                   float* __restrict__ m_ws) {
    __shared__ float xs_red[2 * 64 * 129];   // xs [hh2][c][129]; red aliased on top
    __shared__ float cs[4 * 64 * K9];        // coeffs [row][c][k]
    float* xs = xs_red;
    float* red = xs_red;                      // alias: red [wid][c][9] (2304 floats)
    int tid = threadIdx.x;
    int b  = blockIdx.x >> 5;
    int h0 = (blockIdx.x & 31) << 2;
    int c   = tid & 63;
    int wid = tid >> 6;          // 0..3
    int hh2 = wid >> 1;          // row within chunk
    int q   = wid & 1;           // w-half
    int qu  = __builtin_amdgcn_readfirstlane(q);
    const float* tpq = Tpt16 + qu * 64 * 16;
    const float* xb = x + (size_t)b * 1048576;

    for (int ch = 0; ch < 2; ++ch) {
        __syncthreads();                       // protect red/xs from prior readers
        // stage rows h0+2ch, h0+2ch+1 : [hh2s][c][129], b32 writes (2-way, free)
        for (int it = 0; it < 16; ++it) {
            int e = it * 256 + tid;            // float4 index over 2 rows
            int hh2s = e >> 11;
            int e2 = e & 2047;
            int cc = e2 >> 5;
            int w4 = (e2 & 31) << 2;
            float4 v = *(const float4*)(xb + (size_t)cc * 16384 +
                                        (size_t)(h0 + ch * 2 + hh2s) * 128 + w4);
            float* dst = &xs[hh2s * 8256 + cc * 129 + w4];
            dst[0] = v.x; dst[1] = v.y; dst[2] = v.z; dst[3] = v.w;
        }
        __syncthreads();
        // analysis: acc[k] = sum_{w in half} xs[hh2][c][w] * Tp[k][w]
        float acc[K9];
#pragma unroll
        for (int k = 0; k < K9; ++k) acc[k] = 0.f;
        const float* xr = &xs[hh2 * 8256 + c * 129 + qu * 64];
        for (int w6 = 0; w6 < 64; ++w6) {
            float xv = xr[w6];
            const float* tr = tpq + w6 * 16;   // uniform address -> s_load
#pragma unroll
            for (int k = 0; k < K9; ++k) acc[k] = fmaf(xv, tr[k], acc[k]);
        }
        __syncthreads();                       // xs reads done; red may overwrite
        float* rw = &red[(wid * 64 + c) * K9];
#pragma unroll
        for (int k = 0; k < K9; ++k) rw[k] = acc[k];
        __syncthreads();
        // reduce the two w-halves -> cs[row][c][k]
        for (int idx = tid; idx < 2 * 64 * K9; idx += 256) {
            int hh2r = idx / 576, rem = idx - hh2r * 576;
            float v0 = red[(2 * hh2r) * 576 + rem];
            float v1 = red[(2 * hh2r + 1) * 576 + rem];
            cs[(ch * 2 + hh2r) * 576 + rem] = v0 + v1;
        }
    }
    __syncthreads();
    // channel mix: m[o][k] = sum_c cs[row][c][k] * Wt_w[k][c][o]
    float* mrow = m_ws + (size_t)(b * 128 + h0) * 576;
    for (int idx = tid; idx < 576; idx += 256) {
        int o = idx & 63, k = idx >> 6;        // k uniform per wave -> cs broadcast
        const float* wt = Wt_w + k * 4096 + o; // lanes over o: coalesced
        float a0 = 0.f, a1 = 0.f, a2 = 0.f, a3 = 0.f;
        for (int cc = 0; cc < 64; ++cc) {
            float wv = wt[cc * 64];
            float i0 = cs[0 * 576 + cc * 9 + k];
            float i1 = cs[1 * 576 + cc * 9 + k];
            float i2 = cs[2 * 576 + cc * 9 + k];
            float i3 = cs[3 * 576 + cc * 9 + k];
            a0 = fmaf(i0, wv, a0); a1 = fmaf(i1, wv, a1);
            a2 = fmaf(i2, wv, a2); a3 = fmaf(i3, wv, a3);
        }
        mrow[0 * 576 + idx] = a0;              // per-row layout [kw][o]
        mrow[1 * 576 + idx] = a1;
        mrow[2 * 576 + idx] = a2;
        mrow[3 * 576 + idx] = a3;
    }
}

// ---------------- K2: m -> e  (height analysis + channel mix) ---------------
// grid = (b, kh) = 288 blocks x 256 threads.
//   d[kw][o] = sum_h Tp[kh][h] * m[b][h][kw][o]   (coalesced m reads)
//   e[f][kw] = sum_o Wh_t[kh][o][f] * d[kw][o]    (d broadcast from LDS)
__global__ __launch_bounds__(256) void k2_height(const float* __restrict__ m_ws,
                                                 const float* __restrict__ Wh_t,
                                                 const float* __restrict__ Tp,
                                                 float* __restrict__ e_ws) {
    __shared__ float dl[576];      // d [kw][o]
    int tid = threadIdx.x;
    int b  = blockIdx.x / K9;
    int kh = blockIdx.x - b * K9;
    const float* mb = m_ws + (size_t)b * 73728;
    const float* tpr = Tp + kh * 128;          // uniform -> s_load
    int p0 = tid, p1 = tid + 256, p2 = tid + 512;
    bool v2 = (p2 < 576);
    float a0 = 0.f, a1 = 0.f, a2 = 0.f;
#pragma unroll 4
    for (int h = 0; h < 128; ++h) {
        float tp = tpr[h];
        const float* mr = mb + (size_t)h * 576;
        a0 = fmaf(tp, mr[p0], a0);
        a1 = fmaf(tp, mr[p1], a1);
        if (v2) a2 = fmaf(tp, mr[p2], a2);
    }
    dl[p0] = a0;
    dl[p1] = a1;
    if (v2) dl[p2] = a2;
    __syncthreads();
    float* eb = e_ws + (size_t)b * 5184;
    for (int idx = tid; idx < 576; idx += 256) {
        int kw = idx >> 6, f = idx & 63;       // lanes over f
        const float* wh = Wh_t + kh * 4096 + f;
        const float* dr = &dl[kw * 64];
        float acc = 0.f;
        for (int o = 0; o < 64; ++o)
            acc = fmaf(wh[o * 64], dr[o], acc); // wh coalesced, dr broadcast
        eb[(size_t)f * 81 + kh * 9 + kw] = acc; // e layout [b][f][kh*9+kw]
    }
}

// ---------------- K3: e -> out (separable synthesis) ------------------------
// block = (b, f). f1[kh][w] = sum_kw e*Te_w; out = sum_kh Te_h*f1.
__global__ __launch_bounds__(256) void k3_synth(const float* __restrict__ e_ws,
                                                const float* __restrict__ Te,
                                                float* __restrict__ out) {
    __shared__ float tes[1152];   // Te [n][k], stride 9
    __shared__ float el[81];
    __shared__ float f1[9 * 128];
    int tid = threadIdx.x;
    int bf = blockIdx.x;
    for (int i = tid; i < 1152; i += 256) tes[i] = Te[i];
    if (tid < 81) el[tid] = e_ws[(size_t)bf * 81 + tid];
    __syncthreads();
    for (int idx = tid; idx < 1152; idx += 256) {
        int kh = idx >> 7, w = idx & 127;
        float acc = 0.f;
#pragma unroll
        for (int kw = 0; kw < 9; ++kw)
            acc = fmaf(el[kh * 9 + kw], tes[w * 9 + kw], acc);
        f1[kh * 128 + w] = acc;
    }
    __syncthreads();
    int w4 = (tid & 31) << 2;
    int hg = tid >> 5;                 // 0..7
    float4 fr[9];
#pragma unroll
    for (int k = 0; k < 9; ++k) fr[k] = *(const float4*)&f1[k * 128 + w4];
    float* ob = out + (size_t)bf * 16384;
    for (int h = hg; h < 128; h += 8) {
        const float* th = &tes[h * 9];
        float4 acc = make_float4(0.f, 0.f, 0.f, 0.f);
#pragma unroll
        for (int k = 0; k < 9; ++k) {
            float t = th[k];           // broadcast read
            acc.x = fmaf(t, fr[k].x, acc.x);
            acc.y = fmaf(t, fr[k].y, acc.y);
            acc.z = fmaf(t, fr[k].z, acc.z);
            acc.w = fmaf(t, fr[k].w, acc.w);
        }
        *(float4*)(ob + h * 128 + w4) = acc;   // coalesced float4 store
    }
}

extern "C" void kernel_launch(void* const* d_in, const int* in_sizes, int n_in,
                              void* d_out, int out_size, void* d_ws, size_t ws_size,
                              hipStream_t stream) {
    (void)in_sizes; (void)n_in; (void)out_size; (void)ws_size;
    const float* x  = (const float*)d_in[0];
    const float* Ww = (const float*)d_in[1];
    const float* Wh = (const float*)d_in[2];
    float* out = (float*)d_out;
    float* ws = (float*)d_ws;
    // workspace layout (floats): total 2,603,264 (~10.4 MB)
    float* Tp    = ws;                        // 1152
    float* Te    = ws + 1152;                 // 1152
    float* Tpt16 = ws + 2304;                 // 2048
    float* Wt_w  = ws + 4352;                 // 36864
    float* Wh_t  = ws + 41216;                // 36864
    float* m_ws  = ws + 78080;                // 2,359,296
    float* e_ws  = ws + 78080 + 2359296;      // 165,888

    setup_cheb<<<1, 128, 0, stream>>>(Tp, Te, Tpt16);
    transpose_w<<<288, 256, 0, stream>>>(Ww, Wh, Wt_w, Wh_t);
    k1_width<<<1024, 256, 0, stream>>>(x, Wt_w, Tpt16, m_ws);
    k2_height<<<288, 256, 0, stream>>>(m_ws, Wh_t, Tp, e_ws);
    k3_synth<<<2048, 256, 0, stream>>>(e_ws, Te, out);
}

// Round 3
// 332.680 us; speedup vs baseline: 1.4464x; 1.0660x over previous
//
#include <hip/hip_runtime.h>
#include <math.h>

// ChebConv2D on MI355X (gfx950).
//   m[b,h,kw,o]   = sum_c (sum_w x[b,c,h,w] Tp_w[kw,w]) W_w[c,o,kw]     (K1)
//   d[b,kh,kw,o]  = sum_h Tp_h[kh,h] m[b,h,kw,o]                        (K2 ph1)
//   e[b,f,kh,kw]  = sum_o W_h[o,f,kh] d[b,kh,kw,o]                      (K2 ph2)
//   out[b,f,h,w]  = sum_kh Te_h[h,kh] sum_kw e[b,f,kh,kw] Te_w[w,kw]    (K3)

#define K9 9

// ---- setup (fused): block 0 builds Cheb mats; blocks 1..288 transpose W ----
// Tp = pinv(T) = (T^T T)^-1 T^T  (f64, parallel Gauss-Jordan, no pivot: SPD)
// Wt_w[k][c][o] <- W_w[c][o][k];  Wh_t[k][o][f] <- W_h[o][f][k]
__global__ __launch_bounds__(256) void setup_all(const float* __restrict__ Ww,
                                                 const float* __restrict__ Wh,
                                                 float* __restrict__ Tp,
                                                 float* __restrict__ Te,
                                                 float* __restrict__ Tpt16,
                                                 float* __restrict__ Wt_w,
                                                 float* __restrict__ Wh_t) {
    int tid = threadIdx.x;
    if (blockIdx.x != 0) {
        int gid = (blockIdx.x - 1) * 256 + tid;
        if (gid < 36864) {
            int k = gid / 4096, r = gid % 4096, c = r / 64, o = r % 64;
            Wt_w[gid] = Ww[(c * 64 + o) * 9 + k];
        } else if (gid < 73728) {
            int g = gid - 36864;
            int k = g / 4096, r = g % 4096, o = r / 64, f = r % 64;
            Wh_t[g] = Wh[(o * 64 + f) * 9 + k];
        }
        return;
    }
    __shared__ double Tsh[128 * K9];
    __shared__ double GA[9][18];   // augmented [G | I] -> [I | G^-1]
    if (tid < 128) {
        int n = tid;
        float xf = (float)((double)n / 127.0);       // np.linspace(0,1,128)
        float xn = 2.0f * xf - 1.0f;
        const float lo = (float)(-1.0 + 1e-6);
        const float hi = (float)(1.0 - 1e-6);
        xn = fminf(fmaxf(xn, lo), hi);
        float th = acosf(xn);
        for (int k = 0; k < K9; ++k) {
            float tv = cosf(th * (float)k);          // f32 like numpy, then f64 cast
            Te[n * K9 + k] = tv;
            Tsh[n * K9 + k] = (double)tv;
        }
    }
    __syncthreads();
    if (tid < 81) {                                   // G = T^T T  (9x9, f64)
        int i = tid / 9, j = tid % 9;
        double s = 0.0;
        for (int n = 0; n < 128; ++n) s += Tsh[n * K9 + i] * Tsh[n * K9 + j];
        GA[i][j] = s;
    }
    if (tid >= 81 && tid < 162) {                     // right half: identity
        int i = (tid - 81) / 9, j = (tid - 81) % 9;
        GA[i][9 + j] = (i == j) ? 1.0 : 0.0;
    }
    __syncthreads();
    int r18 = tid / 18, j18 = tid % 18;
    for (int col = 0; col < 9; ++col) {               // GJ, parallel, no pivot (SPD)
        double inv = 0.0;
        if (tid < 18) inv = 1.0 / GA[col][col];
        __syncthreads();
        if (tid < 18) GA[col][tid] *= inv;
        __syncthreads();
        double f = 0.0;
        if (tid < 162 && r18 != col) f = GA[r18][col];
        __syncthreads();
        if (tid < 162 && r18 != col) GA[r18][j18] -= f * GA[col][j18];
        __syncthreads();
    }
    // Tp[k][n] = sum_j Ginv[k][j] * T[n][j]
    for (int idx = tid; idx < K9 * 128; idx += 256) {
        int k = idx / 128, n = idx % 128;
        double s = 0.0;
        for (int j = 0; j < 9; ++j) s += GA[k][9 + j] * Tsh[n * K9 + j];
        float sv = (float)s;
        Tp[idx] = sv;
        Tpt16[n * 16 + k] = sv;      // transposed, padded row of 16 for s_load
    }
}

// ---------------- K1: x -> m  (width analysis + channel mix) ----------------
// block = (b, group of 4 h rows), 256 threads. m layout: [b][h][kw][o].
// Analysis: thread=(row-in-chunk hh2, w-half q, channel c). x staged at stride
// 129 (lane-over-c reads conflict-free). Tp via wave-uniform scalar loads from
// Tpt16; #pragma unroll 8 batches the s_loads so K$ latency hides under FMAs.
__global__ __launch_bounds__(256, 2) void k1_width(const float* __restrict__ x,
                                                   const float* __restrict__ Wt_w,
                                                   const float* __restrict__ Tpt16,
                                                   float* __restrict__ m_ws) {
    __shared__ float xs_red[2 * 64 * 129];   // xs [hh2][c][129]; red aliased on top
    __shared__ float cs[4 * 64 * K9];        // coeffs [row][c][k]
    float* xs = xs_red;
    float* red = xs_red;                      // alias: red [wid][c][9] (2304 floats)
    int tid = threadIdx.x;
    int b  = blockIdx.x >> 5;
    int h0 = (blockIdx.x & 31) << 2;
    int c   = tid & 63;
    int wid = tid >> 6;          // 0..3
    int hh2 = wid >> 1;          // row within chunk
    int q   = wid & 1;           // w-half
    int qu  = __builtin_amdgcn_readfirstlane(q);
    const float* tpq = Tpt16 + qu * 64 * 16;
    const float* xb = x + (size_t)b * 1048576;

    for (int ch = 0; ch < 2; ++ch) {
        __syncthreads();                       // protect red/xs from prior readers
        // stage rows h0+2ch, h0+2ch+1 : [hh2s][c][129], b32 writes (2-way, free)
        for (int it = 0; it < 16; ++it) {
            int e = it * 256 + tid;            // float4 index over 2 rows
            int hh2s = e >> 11;
            int e2 = e & 2047;
            int cc = e2 >> 5;
            int w4 = (e2 & 31) << 2;
            float4 v = *(const float4*)(xb + (size_t)cc * 16384 +
                                        (size_t)(h0 + ch * 2 + hh2s) * 128 + w4);
            float* dst = &xs[hh2s * 8256 + cc * 129 + w4];
            dst[0] = v.x; dst[1] = v.y; dst[2] = v.z; dst[3] = v.w;
        }
        __syncthreads();
        // analysis: acc[k] = sum_{w in half} xs[hh2][c][w] * Tp[k][w]
        float acc[K9];
#pragma unroll
        for (int k = 0; k < K9; ++k) acc[k] = 0.f;
        const float* xr = &xs[hh2 * 8256 + c * 129 + qu * 64];
#pragma unroll 8
        for (int w6 = 0; w6 < 64; ++w6) {
            float xv = xr[w6];
            const float* tr = tpq + w6 * 16;   // uniform address -> batched s_load
#pragma unroll
            for (int k = 0; k < K9; ++k) acc[k] = fmaf(xv, tr[k], acc[k]);
        }
        __syncthreads();                       // xs reads done; red may overwrite
        float* rw = &red[(wid * 64 + c) * K9];
#pragma unroll
        for (int k = 0; k < K9; ++k) rw[k] = acc[k];
        __syncthreads();
        // reduce the two w-halves -> cs[row][c][k]
        for (int idx = tid; idx < 2 * 64 * K9; idx += 256) {
            int hh2r = idx / 576, rem = idx - hh2r * 576;
            float v0 = red[(2 * hh2r) * 576 + rem];
            float v1 = red[(2 * hh2r + 1) * 576 + rem];
            cs[(ch * 2 + hh2r) * 576 + rem] = v0 + v1;
        }
    }
    __syncthreads();
    // channel mix: m[o][k] = sum_c cs[row][c][k] * Wt_w[k][c][o]
    float* mrow = m_ws + (size_t)(b * 128 + h0) * 576;
    for (int idx = tid; idx < 576; idx += 256) {
        int o = idx & 63, k = idx >> 6;        // k uniform per wave -> cs broadcast
        const float* wt = Wt_w + k * 4096 + o; // lanes over o: coalesced
        float a0 = 0.f, a1 = 0.f, a2 = 0.f, a3 = 0.f;
        for (int cc = 0; cc < 64; ++cc) {
            float wv = wt[cc * 64];
            float i0 = cs[0 * 576 + cc * 9 + k];
            float i1 = cs[1 * 576 + cc * 9 + k];
            float i2 = cs[2 * 576 + cc * 9 + k];
            float i3 = cs[3 * 576 + cc * 9 + k];
            a0 = fmaf(i0, wv, a0); a1 = fmaf(i1, wv, a1);
            a2 = fmaf(i2, wv, a2); a3 = fmaf(i3, wv, a3);
        }
        mrow[0 * 576 + idx] = a0;              // per-row layout [kw][o]
        mrow[1 * 576 + idx] = a1;
        mrow[2 * 576 + idx] = a2;
        mrow[3 * 576 + idx] = a3;
    }
}

// ---------------- K2: m -> e  (height analysis + channel mix) ---------------
// grid = (b, kh) = 288 blocks x 256 threads.
//   d[kw][o] = sum_h Tp[kh][h] * m[b][h][kw][o]   (coalesced m reads)
//   e[f][kw] = sum_o Wh_t[kh][o][f] * d[kw][o]    (d broadcast from LDS)
__global__ __launch_bounds__(256) void k2_height(const float* __restrict__ m_ws,
                                                 const float* __restrict__ Wh_t,
                                                 const float* __restrict__ Tp,
                                                 float* __restrict__ e_ws) {
    __shared__ float dl[576];      // d [kw][o]
    int tid = threadIdx.x;
    int b  = blockIdx.x / K9;
    int kh = blockIdx.x - b * K9;
    const float* mb = m_ws + (size_t)b * 73728;
    const float* tpr = Tp + kh * 128;          // uniform -> s_load
    int p0 = tid, p1 = tid + 256, p2 = tid + 512;
    bool v2 = (p2 < 576);
    float a0 = 0.f, a1 = 0.f, a2 = 0.f;
#pragma unroll 4
    for (int h = 0; h < 128; ++h) {
        float tp = tpr[h];
        const float* mr = mb + (size_t)h * 576;
        a0 = fmaf(tp, mr[p0], a0);
        a1 = fmaf(tp, mr[p1], a1);
        if (v2) a2 = fmaf(tp, mr[p2], a2);
    }
    dl[p0] = a0;
    dl[p1] = a1;
    if (v2) dl[p2] = a2;
    __syncthreads();
    float* eb = e_ws + (size_t)b * 5184;
    for (int idx = tid; idx < 576; idx += 256) {
        int kw = idx >> 6, f = idx & 63;       // lanes over f
        const float* wh = Wh_t + kh * 4096 + f;
        const float* dr = &dl[kw * 64];
        float acc = 0.f;
        for (int o = 0; o < 64; ++o)
            acc = fmaf(wh[o * 64], dr[o], acc); // wh coalesced, dr broadcast
        eb[(size_t)f * 81 + kh * 9 + kw] = acc; // e layout [b][f][kh*9+kw]
    }
}

// ---------------- K3: e -> out (separable synthesis) ------------------------
// block = (b, f). f1[kh][w] = sum_kw e*Te_w; out = sum_kh Te_h*f1.
__global__ __launch_bounds__(256) void k3_synth(const float* __restrict__ e_ws,
                                                const float* __restrict__ Te,
                                                float* __restrict__ out) {
    __shared__ float tes[1152];   // Te [n][k], stride 9
    __shared__ float el[81];
    __shared__ float f1[9 * 128];
    int tid = threadIdx.x;
    int bf = blockIdx.x;
    for (int i = tid; i < 1152; i += 256) tes[i] = Te[i];
    if (tid < 81) el[tid] = e_ws[(size_t)bf * 81 + tid];
    __syncthreads();
    for (int idx = tid; idx < 1152; idx += 256) {
        int kh = idx >> 7, w = idx & 127;
        float acc = 0.f;
#pragma unroll
        for (int kw = 0; kw < 9; ++kw)
            acc = fmaf(el[kh * 9 + kw], tes[w * 9 + kw], acc);
        f1[kh * 128 + w] = acc;
    }
    __syncthreads();
    int w4 = (tid & 31) << 2;
    int hg = tid >> 5;                 // 0..7
    float4 fr[9];
#pragma unroll
    for (int k = 0; k < 9; ++k) fr[k] = *(const float4*)&f1[k * 128 + w4];
    float* ob = out + (size_t)bf * 16384;
    for (int h = hg; h < 128; h += 8) {
        const float* th = &tes[h * 9];
        float4 acc = make_float4(0.f, 0.f, 0.f, 0.f);
#pragma unroll
        for (int k = 0; k < 9; ++k) {
            float t = th[k];           // broadcast read
            acc.x = fmaf(t, fr[k].x, acc.x);
            acc.y = fmaf(t, fr[k].y, acc.y);
            acc.z = fmaf(t, fr[k].z, acc.z);
            acc.w = fmaf(t, fr[k].w, acc.w);
        }
        *(float4*)(ob + h * 128 + w4) = acc;   // coalesced float4 store
    }
}

extern "C" void kernel_launch(void* const* d_in, const int* in_sizes, int n_in,
                              void* d_out, int out_size, void* d_ws, size_t ws_size,
                              hipStream_t stream) {
    (void)in_sizes; (void)n_in; (void)out_size; (void)ws_size;
    const float* x  = (const float*)d_in[0];
    const float* Ww = (const float*)d_in[1];
    const float* Wh = (const float*)d_in[2];
    float* out = (float*)d_out;
    float* ws = (float*)d_ws;
    // workspace layout (floats): total 2,603,264 (~10.4 MB)
    float* Tp    = ws;                        // 1152
    float* Te    = ws + 1152;                 // 1152
    float* Tpt16 = ws + 2304;                 // 2048
    float* Wt_w  = ws + 4352;                 // 36864
    float* Wh_t  = ws + 41216;                // 36864
    float* m_ws  = ws + 78080;                // 2,359,296
    float* e_ws  = ws + 78080 + 2359296;      // 165,888

    setup_all<<<289, 256, 0, stream>>>(Ww, Wh, Tp, Te, Tpt16, Wt_w, Wh_t);
    k1_width<<<1024, 256, 0, stream>>>(x, Wt_w, Tpt16, m_ws);
    k2_height<<<288, 256, 0, stream>>>(m_ws, Wh_t, Tp, e_ws);
    k3_synth<<<2048, 256, 0, stream>>>(e_ws, Te, out);
}